// Round 1
// baseline (14958.147 us; speedup 1.0000x reference)
//
#include <hip/hip_runtime.h>
#include <hip/hip_bf16.h>
#include <math.h>

// Problem dims
// V=32000 E=512 H=1024 A=1024 L=2 B=16 T=64 S=64
// ws usage ~74MB (assumed available).

typedef __bf16 bf16x8 __attribute__((ext_vector_type(8)));
typedef float  f32x4  __attribute__((ext_vector_type(4)));

__device__ __forceinline__ float sigm(float x){ return 1.0f/(1.0f+expf(-x)); }

// ---------- transpose: in[R][C] -> out[C][R], R,C multiples of 32 ----------
__global__ __launch_bounds__(256) void k_transpose(const float* __restrict__ in,
                                                   float* __restrict__ out, int R, int C){
  __shared__ float tile[32][33];
  int c0 = blockIdx.x*32, r0 = blockIdx.y*32;
  int tx = threadIdx.x & 31, ty = threadIdx.x >> 5;
  for(int i=ty;i<32;i+=8) tile[i][tx] = in[(size_t)(r0+i)*C + c0+tx];
  __syncthreads();
  for(int i=ty;i<32;i+=8) out[(size_t)(c0+i)*R + r0+tx] = tile[tx][i];
}

// ---------- gather: emb_tok[(t*16+b)][e] = emb[tgt[b][t]][e] ----------
__global__ __launch_bounds__(256) void k_gather(const int* __restrict__ tgt,
                                                const float* __restrict__ emb,
                                                float* __restrict__ emb_tok){
  int m = blockIdx.x;            // 0..1023, m = t*16+b
  int t = m >> 4, b = m & 15;
  int row = tgt[b*64 + t];
  const float* src = emb + (size_t)row*512;
  float* dst = emb_tok + (size_t)m*512;
  for(int e=threadIdx.x;e<512;e+=256) dst[e] = src[e];
}

// ---------- fp32 GEMM, B^T form: C[m][n] = sum_k A[m][k]*Bt[n][k] (+bias[n]) ----------
// grid = (M/64, N/64); K multiple of 32.
__global__ __launch_bounds__(256) void k_gemm_bt(
    const float* __restrict__ A, int lda,
    const float* __restrict__ Bt, int ldb,
    const float* __restrict__ bias,
    float* __restrict__ C, int N, int K)
{
  __shared__ float As[64][33];
  __shared__ float Bs[64][33];
  int m0 = blockIdx.x*64, n0 = blockIdx.y*64;
  int tid = threadIdx.x;
  int lr = tid >> 2;            // 0..63
  int lk = (tid & 3) * 8;       // 0,8,16,24
  int tm = (tid >> 4) * 4;
  int tn = (tid & 15) * 4;
  float acc[4][4] = {};
  for(int k0=0;k0<K;k0+=32){
    const float* ap = A  + (size_t)(m0+lr)*lda + k0 + lk;
    const float* bp = Bt + (size_t)(n0+lr)*ldb + k0 + lk;
    float4 a0 = *(const float4*)ap, a1 = *(const float4*)(ap+4);
    float4 b0 = *(const float4*)bp, b1 = *(const float4*)(bp+4);
    __syncthreads();
    As[lr][lk+0]=a0.x; As[lr][lk+1]=a0.y; As[lr][lk+2]=a0.z; As[lr][lk+3]=a0.w;
    As[lr][lk+4]=a1.x; As[lr][lk+5]=a1.y; As[lr][lk+6]=a1.z; As[lr][lk+7]=a1.w;
    Bs[lr][lk+0]=b0.x; Bs[lr][lk+1]=b0.y; Bs[lr][lk+2]=b0.z; Bs[lr][lk+3]=b0.w;
    Bs[lr][lk+4]=b1.x; Bs[lr][lk+5]=b1.y; Bs[lr][lk+6]=b1.z; Bs[lr][lk+7]=b1.w;
    __syncthreads();
    #pragma unroll
    for(int kk=0;kk<32;++kk){
      float av[4], bv[4];
      #pragma unroll
      for(int i=0;i<4;++i){ av[i]=As[tm+i][kk]; bv[i]=Bs[tn+i][kk]; }
      #pragma unroll
      for(int i=0;i<4;++i)
        #pragma unroll
        for(int j=0;j<4;++j) acc[i][j] = fmaf(av[i], bv[j], acc[i][j]);
    }
  }
  #pragma unroll
  for(int i=0;i<4;++i)
    #pragma unroll
    for(int j=0;j<4;++j){
      int n = n0+tn+j;
      C[(size_t)(m0+tm+i)*N + n] = acc[i][j] + (bias? bias[n] : 0.f);
    }
}

// ---------- stage A: gh0 = h0@Whh0^T+b_hh0 ; gh1 = h1@Whh1^T+b_hh1 ;
//                      attn score partials (q = h1@Wq then tanh-scores) ----------
// grid = 96 (gh) + 64 (attn) = 160 blocks of 256.
__global__ __launch_bounds__(256) void k_stepA(
    const float* __restrict__ h0, const float* __restrict__ h1,
    const float* __restrict__ Whh0T, const float* __restrict__ Whh1T,
    const float* __restrict__ b_hh0, const float* __restrict__ b_hh1,
    const float* __restrict__ Wq, const float* __restrict__ v_att,
    const float* __restrict__ kp,
    float* __restrict__ gh0, float* __restrict__ gh1,
    float* __restrict__ parts)
{
  __shared__ float smem[16*1032];
  int blk = blockIdx.x, tid = threadIdx.x;
  if(blk < 96){
    const float* h  = (blk<48)? h0 : h1;
    const float* Wt = (blk<48)? Whh0T : Whh1T;
    const float* bb = (blk<48)? b_hh0 : b_hh1;
    float* outp     = (blk<48)? gh0 : gh1;
    int j0 = (blk % 48)*64;
    for(int i=tid;i<16*1024;i+=256) smem[(i>>10)*1032 + (i&1023)] = h[i];
    __syncthreads();
    int j  = j0 + (tid & 63);
    int bg = (tid >> 6) * 4;           // this thread's 4 batch rows
    const float* hb = smem + bg*1032;
    const float* wp = Wt + j;
    float acc0=0.f,acc1=0.f,acc2=0.f,acc3=0.f;
    #pragma unroll 4
    for(int hh=0; hh<1024; ++hh){
      float w = wp[(size_t)hh*3072];
      acc0 = fmaf(w, hb[hh],        acc0);
      acc1 = fmaf(w, hb[1032+hh],   acc1);
      acc2 = fmaf(w, hb[2*1032+hh], acc2);
      acc3 = fmaf(w, hb[3*1032+hh], acc3);
    }
    float bv = bb[j];
    outp[(size_t)(bg+0)*3072 + j] = acc0+bv;
    outp[(size_t)(bg+1)*3072 + j] = acc1+bv;
    outp[(size_t)(bg+2)*3072 + j] = acc2+bv;
    outp[(size_t)(bg+3)*3072 + j] = acc3+bv;
  } else {
    int blk2 = blk - 96;               // 0..63
    int b  = blk2 >> 2;
    int a0 = (blk2 & 3) << 8;          // a-slice of 256
    float* h1s = smem;                 // [1024]
    float* qs  = smem + 1024;          // [256]
    for(int i=tid;i<1024;i+=256) h1s[i] = h1[b*1024 + i];
    __syncthreads();
    int a = a0 + tid;
    float q = 0.f;
    #pragma unroll 4
    for(int hh=0;hh<1024;++hh) q = fmaf(h1s[hh], Wq[(size_t)hh*1024 + a], q);
    qs[tid] = q;
    __syncthreads();
    int s = tid >> 2, part = tid & 3;
    const float* kprow = kp + ((size_t)(b*64+s))*1024 + a0;
    float acc = 0.f;
    #pragma unroll 4
    for(int i=0;i<64;++i){
      int al = part*64 + i;
      acc += v_att[a0+al]*tanhf(qs[al] + kprow[al]);
    }
    acc += __shfl_xor(acc,1);
    acc += __shfl_xor(acc,2);
    if(part==0) parts[(size_t)(b*64+s)*4 + (blk2&3)] = acc;
  }
}

// ---------- stage C: softmax + xgates (attn . EW) + GRU0 combine -> h0n ----------
// grid = 64 blocks of 256; thread = (b = tid>>4, jl = tid&15), jh = blk*16+jl
__global__ __launch_bounds__(256) void k_stepC(
    int t, const float* __restrict__ parts, const float* __restrict__ EW,
    const float* __restrict__ GX0x, const float* __restrict__ gh0,
    const float* __restrict__ h0_in, float* __restrict__ h0_out)
{
  __shared__ float sc[16][64];
  __shared__ float sminv[16];
  int tid = threadIdx.x;
  int b = tid >> 4, si = tid & 15;
  for(int k=0;k<4;++k){
    int s = si + 16*k;
    const float* p = parts + (size_t)(b*64+s)*4;
    sc[b][s] = p[0]+p[1]+p[2]+p[3];
  }
  __syncthreads();
  if(tid < 16){
    float m = -1e30f;
    for(int s=0;s<64;++s) m = fmaxf(m, sc[tid][s]);
    float su = 0.f;
    for(int s=0;s<64;++s){ float e = expf(sc[tid][s]-m); sc[tid][s]=e; su+=e; }
    sminv[tid] = 1.0f/su;
  }
  __syncthreads();
  int jh = blockIdx.x*16 + si;
  float inv = sminv[b];
  float xr=0.f,xz=0.f,xn=0.f;
  const float* ewb = EW + (size_t)b*64*3072;
  #pragma unroll 4
  for(int s=0;s<64;++s){
    float a = sc[b][s]*inv;
    const float* e = ewb + (size_t)s*3072;
    xr = fmaf(a, e[jh],      xr);
    xz = fmaf(a, e[jh+1024], xz);
    xn = fmaf(a, e[jh+2048], xn);
  }
  const float* gx = GX0x + ((size_t)t*16 + b)*3072;
  xr += gx[jh]; xz += gx[jh+1024]; xn += gx[jh+2048];
  const float* gh = gh0 + (size_t)b*3072;
  float r = sigm(xr + gh[jh]);
  float z = sigm(xz + gh[jh+1024]);
  float n = tanhf(xn + r*gh[jh+2048]);
  float hp = h0_in[b*1024 + jh];
  h0_out[b*1024 + jh] = (1.f-z)*n + z*hp;
}

// ---------- stage D: g1x = h0n@Wih1^T+b_ih1 ; GRU1 combine -> h1n ; store Hseq ----------
// grid = 64 blocks of 256
__global__ __launch_bounds__(256) void k_stepD(
    int t, const float* __restrict__ h0n, const float* __restrict__ Wih1T,
    const float* __restrict__ b_ih1, const float* __restrict__ gh1,
    const float* __restrict__ h1_in, float* __restrict__ h1_out,
    float* __restrict__ Hseq)
{
  __shared__ float hs[16*1032];
  int tid = threadIdx.x;
  for(int i=tid;i<16*1024;i+=256) hs[(i>>10)*1032 + (i&1023)] = h0n[i];
  __syncthreads();
  int jl = tid & 15, b = tid >> 4;
  int jh = blockIdx.x*16 + jl;
  const float* hb = hs + b*1032;
  const float* w  = Wih1T + jh;
  float xr=0.f,xz=0.f,xn=0.f;
  #pragma unroll 4
  for(int hh=0;hh<1024;++hh){
    float hv = hb[hh];
    size_t o = (size_t)hh*3072;
    xr = fmaf(hv, w[o],        xr);
    xz = fmaf(hv, w[o+1024],   xz);
    xn = fmaf(hv, w[o+2048],   xn);
  }
  xr += b_ih1[jh]; xz += b_ih1[jh+1024]; xn += b_ih1[jh+2048];
  const float* gh = gh1 + (size_t)b*3072;
  float r = sigm(xr + gh[jh]);
  float z = sigm(xz + gh[jh+1024]);
  float n = tanhf(xn + r*gh[jh+2048]);
  float hp = h1_in[b*1024 + jh];
  float hnew = (1.f-z)*n + z*hp;
  h1_out[b*1024 + jh] = hnew;
  Hseq[((size_t)t*16 + b)*1024 + jh] = hnew;
}

// ---------- fp32 -> bf16 ----------
__global__ __launch_bounds__(256) void k_cvt(const float* __restrict__ in,
                                             __bf16* __restrict__ out){
  int i = blockIdx.x*256 + threadIdx.x;
  out[i] = (__bf16)in[i];
}

// ---------- logits: out[b][t][v] = Hseq_bf16[m=t*16+b] . Wout[v] + b_out[v] ----------
// bf16 MFMA 16x16x32. BM=128, BN=64, BK=32. grid (8, 500), 256 threads (4 waves 2x2).
__global__ __launch_bounds__(256) void k_logits(
    const __bf16* __restrict__ Hb, const float* __restrict__ Wout,
    const float* __restrict__ b_out, float* __restrict__ out)
{
  __shared__ __align__(16) __bf16 As[128][40];
  __shared__ __align__(16) __bf16 Bs[64][40];
  int tid = threadIdx.x;
  int tm0 = blockIdx.x * 128;
  int tn0 = blockIdx.y * 64;
  int lane = tid & 63, wave = tid >> 6;
  int wr = wave >> 1, wc = wave & 1;     // wave tile 64(m) x 32(n)
  int q  = lane >> 4, rr = lane & 15;
  f32x4 acc[4][2] = {};
  int ar = tid >> 1, ak = (tid & 1) * 16;
  int br = tid >> 2, bk = (tid & 3) * 8;
  for(int k0=0;k0<1024;k0+=32){
    bf16x8 av0 = *(const bf16x8*)(Hb + (size_t)(tm0+ar)*1024 + k0 + ak);
    bf16x8 av1 = *(const bf16x8*)(Hb + (size_t)(tm0+ar)*1024 + k0 + ak + 8);
    const float* bp = Wout + (size_t)(tn0+br)*1024 + k0 + bk;
    float4 f0 = *(const float4*)bp;
    float4 f1 = *(const float4*)(bp+4);
    __syncthreads();
    *(bf16x8*)&As[ar][ak]   = av0;
    *(bf16x8*)&As[ar][ak+8] = av1;
    bf16x8 bv;
    bv[0]=(__bf16)f0.x; bv[1]=(__bf16)f0.y; bv[2]=(__bf16)f0.z; bv[3]=(__bf16)f0.w;
    bv[4]=(__bf16)f1.x; bv[5]=(__bf16)f1.y; bv[6]=(__bf16)f1.z; bv[7]=(__bf16)f1.w;
    *(bf16x8*)&Bs[br][bk] = bv;
    __syncthreads();
    bf16x8 af[4], bfr[2];
    #pragma unroll
    for(int mi=0;mi<4;++mi) af[mi]  = *(const bf16x8*)&As[wr*64 + mi*16 + rr][q*8];
    #pragma unroll
    for(int ni=0;ni<2;++ni) bfr[ni] = *(const bf16x8*)&Bs[wc*32 + ni*16 + rr][q*8];
    #pragma unroll
    for(int mi=0;mi<4;++mi)
      #pragma unroll
      for(int ni=0;ni<2;++ni)
        acc[mi][ni] = __builtin_amdgcn_mfma_f32_16x16x32_bf16(af[mi], bfr[ni], acc[mi][ni], 0,0,0);
  }
  #pragma unroll
  for(int mi=0;mi<4;++mi)
    #pragma unroll
    for(int ni=0;ni<2;++ni)
      #pragma unroll
      for(int i=0;i<4;++i){
        int m = tm0 + wr*64 + mi*16 + q*4 + i;
        int v = tn0 + wc*32 + ni*16 + rr;
        int bb = m & 15, tt = m >> 4;
        out[((size_t)bb*64 + tt)*32000 + v] = acc[mi][ni][i] + b_out[v];
      }
}

extern "C" void kernel_launch(void* const* d_in, const int* in_sizes, int n_in,
                              void* d_out, int out_size, void* d_ws, size_t ws_size,
                              hipStream_t stream){
  const int*   tgt    = (const int*)d_in[0];
  const float* hidden = (const float*)d_in[1];
  const float* enc    = (const float*)d_in[2];
  const float* emb    = (const float*)d_in[3];
  const float* Wq     = (const float*)d_in[4];
  const float* Wk     = (const float*)d_in[5];
  const float* v_att  = (const float*)d_in[6];
  const float* W_ih0  = (const float*)d_in[7];
  const float* W_hh0  = (const float*)d_in[8];
  const float* b_ih0  = (const float*)d_in[9];
  const float* b_hh0  = (const float*)d_in[10];
  const float* W_ih1  = (const float*)d_in[11];
  const float* W_hh1  = (const float*)d_in[12];
  const float* b_ih1  = (const float*)d_in[13];
  const float* b_hh1  = (const float*)d_in[14];
  const float* W_out  = (const float*)d_in[15];
  const float* b_out  = (const float*)d_in[16];
  float* out = (float*)d_out;

  float* ws = (float*)d_ws;
  size_t off = 0;
  auto alloc = [&](size_t n){ float* p = ws + off; off += n; return p; };
  float* kp    = alloc((size_t)1024*1024);   // keys_proj [b*64+s][a]
  float* GX0x  = alloc((size_t)1024*3072);   // [t*16+b][3H] = emb_tok@Wx^T + b_ih0
  float* EW    = alloc((size_t)1024*3072);   // [b*64+s][3H] = enc@Wc^T
  float* Whh0T = alloc((size_t)1024*3072);
  float* Whh1T = alloc((size_t)1024*3072);
  float* Wih1T = alloc((size_t)1024*3072);
  float* gh0   = alloc((size_t)16*3072);
  float* gh1   = alloc((size_t)16*3072);
  float* parts = alloc((size_t)16*64*4);
  float* h0a   = alloc((size_t)16*1024);
  float* h0b   = alloc((size_t)16*1024);
  float* h1a   = alloc((size_t)16*1024);
  float* h1b   = alloc((size_t)16*1024);
  float* Hseq  = alloc((size_t)1024*1024);   // [t*16+b][H]
  float* Hb_f  = alloc((size_t)512*1024);    // 1024x1024 bf16
  // aliases (setup-only buffers overlap recurrence-phase buffers):
  float*  WkT     = Hseq;        // Wk^T lives where Hseq will go (used before steps)
  float*  emb_tok = Hb_f;        // emb gather lives where Hb will go
  __bf16* Hb      = (__bf16*)Hb_f;
  (void)ws_size; (void)in_sizes; (void)n_in; (void)out_size;

  // ---- setup (one-time) ----
  k_transpose<<<dim3(32,32),256,0,stream>>>(Wk,    WkT,   1024,1024);
  k_transpose<<<dim3(32,96),256,0,stream>>>(W_hh0, Whh0T, 3072,1024);
  k_transpose<<<dim3(32,96),256,0,stream>>>(W_hh1, Whh1T, 3072,1024);
  k_transpose<<<dim3(32,96),256,0,stream>>>(W_ih1, Wih1T, 3072,1024);
  k_gather<<<1024,256,0,stream>>>(tgt, emb, emb_tok);
  // kp = enc @ Wk   (as A[m,k]*Bt[n,k] with Bt = Wk^T)
  k_gemm_bt<<<dim3(16,16),256,0,stream>>>(enc,1024, WkT,1024, nullptr, kp, 1024,1024);
  // GX0x = emb_tok @ Wx^T + b_ih0   (Wx = W_ih0[:, :512], ldb=1536)
  k_gemm_bt<<<dim3(16,48),256,0,stream>>>(emb_tok,512, W_ih0,1536, b_ih0, GX0x, 3072,512);
  // EW = enc @ Wc^T                 (Wc = W_ih0[:, 512:1536])
  k_gemm_bt<<<dim3(16,48),256,0,stream>>>(enc,1024, W_ih0+512,1536, nullptr, EW, 3072,1024);

  // ---- sequential recurrence: 3 kernels per step ----
  const float* h0_init = hidden;
  const float* h1_init = hidden + 16*1024;
  for(int t=0;t<64;++t){
    const float* h0i = (t==0)? h0_init : ((t&1)? h0b : h0a);
    float*       h0o = (t&1)? h0a : h0b;
    const float* h1i = (t==0)? h1_init : ((t&1)? h1b : h1a);
    float*       h1o = (t&1)? h1a : h1b;
    k_stepA<<<160,256,0,stream>>>(h0i,h1i,Whh0T,Whh1T,b_hh0,b_hh1,Wq,v_att,kp,gh0,gh1,parts);
    k_stepC<<<64,256,0,stream>>>(t, parts, EW, GX0x, gh0, h0i, h0o);
    k_stepD<<<64,256,0,stream>>>(t, h0o, Wih1T, b_ih1, gh1, h1i, h1o, Hseq);
  }

  // ---- deferred logits: bf16 MFMA GEMM ----
  k_cvt<<<(1024*1024)/256,256,0,stream>>>(Hseq, Hb);
  k_logits<<<dim3(8,500),256,0,stream>>>(Hb, W_out, b_out, out);
}

// Round 2
// 4101.934 us; speedup vs baseline: 3.6466x; 3.6466x over previous
//
#include <hip/hip_runtime.h>
#include <hip/hip_bf16.h>
#include <math.h>

// V=32000 E=512 H=1024 A=1024 L=2 B=16 T=64 S=64
typedef __bf16 bf16x8 __attribute__((ext_vector_type(8)));
typedef float  f32x4  __attribute__((ext_vector_type(4)));

__device__ __forceinline__ float sigm(float x){ return 1.0f/(1.0f+expf(-x)); }
__device__ __forceinline__ f32x4 ld4(const float* p){ return *(const f32x4*)p; }

// ---------- transpose ----------
__global__ __launch_bounds__(256) void k_transpose(const float* __restrict__ in,
                                                   float* __restrict__ out, int R, int C){
  __shared__ float tile[32][33];
  int c0 = blockIdx.x*32, r0 = blockIdx.y*32;
  int tx = threadIdx.x & 31, ty = threadIdx.x >> 5;
  for(int i=ty;i<32;i+=8) tile[i][tx] = in[(size_t)(r0+i)*C + c0+tx];
  __syncthreads();
  for(int i=ty;i<32;i+=8) out[(size_t)(c0+i)*R + r0+tx] = tile[tx][i];
}

// ---------- gather ----------
__global__ __launch_bounds__(256) void k_gather(const int* __restrict__ tgt,
                                                const float* __restrict__ emb,
                                                float* __restrict__ emb_tok){
  int m = blockIdx.x;            // m = t*16+b
  int t = m >> 4, b = m & 15;
  int row = tgt[b*64 + t];
  const float* src = emb + (size_t)row*512;
  float* dst = emb_tok + (size_t)m*512;
  for(int e=threadIdx.x;e<512;e+=256) dst[e] = src[e];
}

// ---------- fp32 GEMM, B^T form (setup only) ----------
__global__ __launch_bounds__(256) void k_gemm_bt(
    const float* __restrict__ A, int lda,
    const float* __restrict__ Bt, int ldb,
    const float* __restrict__ bias,
    float* __restrict__ C, int N, int K)
{
  __shared__ float As[64][33];
  __shared__ float Bs[64][33];
  int m0 = blockIdx.x*64, n0 = blockIdx.y*64;
  int tid = threadIdx.x;
  int lr = tid >> 2;
  int lk = (tid & 3) * 8;
  int tm = (tid >> 4) * 4;
  int tn = (tid & 15) * 4;
  float acc[4][4] = {};
  for(int k0=0;k0<K;k0+=32){
    const float* ap = A  + (size_t)(m0+lr)*lda + k0 + lk;
    const float* bp = Bt + (size_t)(n0+lr)*ldb + k0 + lk;
    float4 a0 = *(const float4*)ap, a1 = *(const float4*)(ap+4);
    float4 b0 = *(const float4*)bp, b1 = *(const float4*)(bp+4);
    __syncthreads();
    As[lr][lk+0]=a0.x; As[lr][lk+1]=a0.y; As[lr][lk+2]=a0.z; As[lr][lk+3]=a0.w;
    As[lr][lk+4]=a1.x; As[lr][lk+5]=a1.y; As[lr][lk+6]=a1.z; As[lr][lk+7]=a1.w;
    Bs[lr][lk+0]=b0.x; Bs[lr][lk+1]=b0.y; Bs[lr][lk+2]=b0.z; Bs[lr][lk+3]=b0.w;
    Bs[lr][lk+4]=b1.x; Bs[lr][lk+5]=b1.y; Bs[lr][lk+6]=b1.z; Bs[lr][lk+7]=b1.w;
    __syncthreads();
    #pragma unroll
    for(int kk=0;kk<32;++kk){
      float av[4], bv[4];
      #pragma unroll
      for(int i=0;i<4;++i){ av[i]=As[tm+i][kk]; bv[i]=Bs[tn+i][kk]; }
      #pragma unroll
      for(int i=0;i<4;++i)
        #pragma unroll
        for(int j=0;j<4;++j) acc[i][j] = fmaf(av[i], bv[j], acc[i][j]);
    }
  }
  #pragma unroll
  for(int i=0;i<4;++i)
    #pragma unroll
    for(int j=0;j<4;++j){
      int n = n0+tn+j;
      C[(size_t)(m0+tm+i)*N + n] = acc[i][j] + (bias? bias[n] : 0.f);
    }
}

// ---------- GEMV building block ----------
// out[b][j0..j0+15] = sum_k h[b][k]*W[k][j0..15]; K=1024.
// 256 thr: j4g=tid&3 (4j each), b=(tid>>2)&15, kq=tid>>6 (4 x 256 K-split)
// Deep unroll: 16 float4 W-loads in flight -> BW-bound, not latency-bound.
__device__ __forceinline__ void gemv16(const float* __restrict__ h,
                                       const float* __restrict__ W, int ldw,
                                       float* __restrict__ out, int ldo, int j0,
                                       f32x4 (*red)[16][4])
{
  int tid = threadIdx.x;
  int j4g = tid & 3, b = (tid>>2)&15, kq = tid>>6;
  const float* hp = h + b*1024 + kq*256;
  const float* wp = W + (size_t)(kq*256)*ldw + j0 + j4g*4;
  f32x4 acc = {0.f,0.f,0.f,0.f};
  for(int k0=0;k0<256;k0+=16){
    f32x4 h4[4];
    #pragma unroll
    for(int i=0;i<4;++i) h4[i] = ld4(hp + k0 + i*4);
    f32x4 w[16];
    #pragma unroll
    for(int kk=0;kk<16;++kk) w[kk] = ld4(wp + (size_t)(k0+kk)*ldw);
    #pragma unroll
    for(int kk=0;kk<16;++kk) acc += h4[kk>>2][kk&3] * w[kk];
  }
  red[kq][b][j4g] = acc;
  __syncthreads();
  if(tid < 64){
    int b2 = tid>>2, j2 = tid&3;
    f32x4 s = red[0][b2][j2] + red[1][b2][j2] + red[2][b2][j2] + red[3][b2][j2];
    *(f32x4*)(out + (size_t)b2*ldo + j0 + j2*4) = s;
  }
}

// ---------- bootstrap: gh0(0) ----------
__global__ __launch_bounds__(256) void k_boot(const float* __restrict__ h0,
                                              const float* __restrict__ Whh0T,
                                              float* __restrict__ gh0){
  __shared__ f32x4 red[4][16][4];
  gemv16(h0, Whh0T, 3072, gh0, 3072, blockIdx.x*16, red);
}

// ---------- step K1: gh1 = h1@Whh1^T (192 blk) ; q = h1@Wq (64 blk) ----------
__global__ __launch_bounds__(256) void k_step1(const float* __restrict__ h1,
                                               const float* __restrict__ Whh1T,
                                               float* __restrict__ gh1,
                                               const float* __restrict__ Wq,
                                               float* __restrict__ q){
  __shared__ f32x4 red[4][16][4];
  int blk = blockIdx.x;
  if(blk < 192) gemv16(h1, Whh1T, 3072, gh1, 3072, blk*16, red);
  else          gemv16(h1, Wq,    1024, q,   1024, (blk-192)*16, red);
}

// ---------- step K2: escore[b][s] = exp(sum_a v[a]*tanh(q[b][a]+kp[b,s][a])) ----------
// grid 256: b=blk>>4, s-quad=(blk&15); wave = one s; lane covers 16 a's.
__global__ __launch_bounds__(256) void k_step2(const float* __restrict__ q,
                                               const float* __restrict__ kp,
                                               const float* __restrict__ v_att,
                                               float* __restrict__ escore){
  int b = blockIdx.x >> 4;
  int s = (blockIdx.x & 15)*4 + (threadIdx.x >> 6);
  int lane = threadIdx.x & 63;
  const float* qp  = q  + b*1024 + lane*16;
  const float* kpp = kp + (size_t)(b*64+s)*1024 + lane*16;
  const float* vp  = v_att + lane*16;
  float acc = 0.f;
  #pragma unroll
  for(int i=0;i<4;++i){
    f32x4 qv = ld4(qp+i*4), kv = ld4(kpp+i*4), vv = ld4(vp+i*4);
    #pragma unroll
    for(int e=0;e<4;++e) acc += vv[e]*tanhf(qv[e]+kv[e]);
  }
  #pragma unroll
  for(int o=1;o<64;o<<=1) acc += __shfl_xor(acc, o);
  if(lane==0) escore[b*64+s] = expf(acc);  // |score|<~16, no max-sub needed
}

// ---------- step K3: xg = attn.EW + GX0x ; h0n = GRU0(xg, gh0, h0) ----------
// grid 128 (jh-slice 8): thread (b=tid>>4, j2g=tid&1, sq=(tid>>1)&7): 8-way s-split.
__global__ __launch_bounds__(256) void k_step3(int t,
    const float* __restrict__ escore, const float* __restrict__ EW,
    const float* __restrict__ GX0x, const float* __restrict__ gh0,
    const float* __restrict__ b_hh0,
    const float* __restrict__ h0_in, float* __restrict__ h0_out){
  __shared__ f32x4 red[8][16][2][3];
  int tid = threadIdx.x;
  int b = tid>>4, j2g = tid&1, sq = (tid>>1)&7;
  int jh0 = blockIdx.x*8;
  int j = jh0 + j2g*4;
  f32x4 xr={0.f,0.f,0.f,0.f}, xz=xr, xn=xr;
  const float* ew = EW + (size_t)(b*64 + sq*8)*3072 + j;
  const float* ep = escore + b*64 + sq*8;
  #pragma unroll
  for(int si=0;si<8;++si){
    float e = ep[si];
    const float* r = ew + (size_t)si*3072;
    xr += e*ld4(r); xz += e*ld4(r+1024); xn += e*ld4(r+2048);
  }
  red[sq][b][j2g][0]=xr; red[sq][b][j2g][1]=xz; red[sq][b][j2g][2]=xn;
  __syncthreads();
  if(tid < 32){
    int b2 = tid>>1, jg = tid&1; int jj = jh0 + jg*4;
    f32x4 sr={0.f,0.f,0.f,0.f}, sz=sr, sn=sr;
    #pragma unroll
    for(int k=0;k<8;++k){ sr+=red[k][b2][jg][0]; sz+=red[k][b2][jg][1]; sn+=red[k][b2][jg][2]; }
    float den=0.f;
    const float* ep2 = escore + b2*64;
    #pragma unroll 8
    for(int s2=0;s2<64;++s2) den += ep2[s2];
    float inv = 1.0f/den;
    const float* gx = GX0x + ((size_t)t*16 + b2)*3072 + jj;
    f32x4 gxr = ld4(gx), gxz = ld4(gx+1024), gxn = ld4(gx+2048);
    const float* g0 = gh0 + (size_t)b2*3072 + jj;
    f32x4 hr = ld4(g0)      + ld4(b_hh0+jj);
    f32x4 hz = ld4(g0+1024) + ld4(b_hh0+1024+jj);
    f32x4 hn = ld4(g0+2048) + ld4(b_hh0+2048+jj);
    f32x4 hold = ld4(h0_in + b2*1024 + jj);
    f32x4 hnew;
    #pragma unroll
    for(int e=0;e<4;++e){
      float r = sigm(sr[e]*inv + gxr[e] + hr[e]);
      float z = sigm(sz[e]*inv + gxz[e] + hz[e]);
      float n = tanhf(sn[e]*inv + gxn[e] + r*hn[e]);
      hnew[e] = (1.f-z)*n + z*hold[e];
    }
    *(f32x4*)(h0_out + b2*1024 + jj) = hnew;
  }
}

// ---------- step K4: g1x = h0n@Wih1^T -> h1n (128 blk) ; gh0(t+1) (192 blk) ----------
__global__ __launch_bounds__(256) void k_step4(int t,
    const float* __restrict__ h0n, const float* __restrict__ Wih1T,
    const float* __restrict__ b_ih1,
    const float* __restrict__ gh1, const float* __restrict__ b_hh1,
    const float* __restrict__ h1_in, float* __restrict__ h1_out,
    float* __restrict__ Hseq,
    const float* __restrict__ Whh0T, float* __restrict__ gh0){
  int blk = blockIdx.x;
  if(blk >= 128){
    __shared__ f32x4 redg[4][16][4];
    gemv16(h0n, Whh0T, 3072, gh0, 3072, (blk-128)*16, redg);
    return;
  }
  __shared__ f32x4 red[8][16][2][3];
  int tid = threadIdx.x;
  int j2g = tid&1, b = (tid>>1)&15, kh = tid>>5;   // 2 x 16 x 8
  int jh0 = blk*8, j = jh0 + j2g*4;
  const float* hp = h0n + b*1024 + kh*128;
  const float* wp = Wih1T + (size_t)(kh*128)*3072 + j;
  f32x4 ar={0.f,0.f,0.f,0.f}, az=ar, an=ar;
  for(int k0=0;k0<128;k0+=8){
    f32x4 h4a = ld4(hp + k0), h4b = ld4(hp + k0 + 4);
    #pragma unroll
    for(int kk=0;kk<8;++kk){
      const float* w = wp + (size_t)(k0+kk)*3072;
      float hv = (kk<4)? h4a[kk&3] : h4b[kk&3];
      ar += hv*ld4(w); az += hv*ld4(w+1024); an += hv*ld4(w+2048);
    }
  }
  red[kh][b][j2g][0]=ar; red[kh][b][j2g][1]=az; red[kh][b][j2g][2]=an;
  __syncthreads();
  if(tid < 32){
    int b2 = tid>>1, jg = tid&1; int jj = jh0 + jg*4;
    f32x4 xr={0.f,0.f,0.f,0.f}, xz=xr, xn=xr;
    #pragma unroll
    for(int k=0;k<8;++k){ xr+=red[k][b2][jg][0]; xz+=red[k][b2][jg][1]; xn+=red[k][b2][jg][2]; }
    xr += ld4(b_ih1+jj); xz += ld4(b_ih1+1024+jj); xn += ld4(b_ih1+2048+jj);
    const float* g1 = gh1 + (size_t)b2*3072 + jj;
    f32x4 hr = ld4(g1)      + ld4(b_hh1+jj);
    f32x4 hz = ld4(g1+1024) + ld4(b_hh1+1024+jj);
    f32x4 hn = ld4(g1+2048) + ld4(b_hh1+2048+jj);
    f32x4 hold = ld4(h1_in + b2*1024 + jj);
    f32x4 hnew;
    #pragma unroll
    for(int e=0;e<4;++e){
      float r = sigm(xr[e] + hr[e]);
      float z = sigm(xz[e] + hz[e]);
      float n = tanhf(xn[e] + r*hn[e]);
      hnew[e] = (1.f-z)*n + z*hold[e];
    }
    *(f32x4*)(h1_out + b2*1024 + jj) = hnew;
    *(f32x4*)(Hseq + ((size_t)t*16 + b2)*1024 + jj) = hnew;
  }
}

// ---------- fp32 -> bf16 ----------
__global__ __launch_bounds__(256) void k_cvt(const float* __restrict__ in,
                                             __bf16* __restrict__ out){
  int i = blockIdx.x*256 + threadIdx.x;
  out[i] = (__bf16)in[i];
}

// ---------- logits: BM=256, BN=128, 512 thr (8 waves 4x2), XCD-chunked swizzle ----------
__global__ __launch_bounds__(512) void k_logits(
    const __bf16* __restrict__ Hb, const float* __restrict__ Wout,
    const float* __restrict__ b_out, float* __restrict__ out)
{
  // bijective swizzle: the 4 m-blocks sharing a W_out stripe land on one XCD
  int c = blockIdx.x & 7, j = blockIdx.x >> 3;
  int x = j & 3, y = (j >> 2)*8 + c;
  if(y >= 250) return;
  int tm0 = x*256, tn0 = y*128;
  __shared__ __align__(16) __bf16 As[256][40];
  __shared__ __align__(16) __bf16 Bs[128][40];
  int tid = threadIdx.x;
  int lane = tid & 63, wave = tid >> 6;
  int wr = wave >> 1, wc = wave & 1;     // wave tile 64(m) x 64(n)
  int qq = lane >> 4, rr = lane & 15;
  f32x4 acc[4][4] = {};
  int ar = tid >> 2, ak = (tid & 3) * 8;
  for(int k0=0;k0<1024;k0+=32){
    bf16x8 a0v = *(const bf16x8*)(Hb + (size_t)(tm0+ar)*1024     + k0 + ak);
    bf16x8 a1v = *(const bf16x8*)(Hb + (size_t)(tm0+ar+128)*1024 + k0 + ak);
    const float* bp = Wout + (size_t)(tn0+ar)*1024 + k0 + ak;
    f32x4 f0 = ld4(bp), f1 = ld4(bp+4);
    __syncthreads();
    *(bf16x8*)&As[ar][ak]     = a0v;
    *(bf16x8*)&As[ar+128][ak] = a1v;
    bf16x8 bv;
    #pragma unroll
    for(int i=0;i<4;++i){ bv[i]=(__bf16)f0[i]; bv[4+i]=(__bf16)f1[i]; }
    *(bf16x8*)&Bs[ar][ak] = bv;
    __syncthreads();
    bf16x8 af[4], bfr[4];
    #pragma unroll
    for(int mi=0;mi<4;++mi) af[mi]  = *(const bf16x8*)&As[wr*64 + mi*16 + rr][qq*8];
    #pragma unroll
    for(int ni=0;ni<4;++ni) bfr[ni] = *(const bf16x8*)&Bs[wc*64 + ni*16 + rr][qq*8];
    #pragma unroll
    for(int mi=0;mi<4;++mi)
      #pragma unroll
      for(int ni=0;ni<4;++ni)
        acc[mi][ni] = __builtin_amdgcn_mfma_f32_16x16x32_bf16(af[mi], bfr[ni], acc[mi][ni], 0,0,0);
  }
  #pragma unroll
  for(int mi=0;mi<4;++mi)
    #pragma unroll
    for(int ni=0;ni<4;++ni)
      #pragma unroll
      for(int i=0;i<4;++i){
        int m = tm0 + wr*64 + mi*16 + qq*4 + i;
        int v = tn0 + wc*64 + ni*16 + rr;
        int bb = m & 15, tt = m >> 4;
        out[((size_t)bb*64 + tt)*32000 + v] = acc[mi][ni][i] + b_out[v];
      }
}

extern "C" void kernel_launch(void* const* d_in, const int* in_sizes, int n_in,
                              void* d_out, int out_size, void* d_ws, size_t ws_size,
                              hipStream_t stream){
  const int*   tgt    = (const int*)d_in[0];
  const float* hidden = (const float*)d_in[1];
  const float* enc    = (const float*)d_in[2];
  const float* emb    = (const float*)d_in[3];
  const float* Wq     = (const float*)d_in[4];
  const float* Wk     = (const float*)d_in[5];
  const float* v_att  = (const float*)d_in[6];
  const float* W_ih0  = (const float*)d_in[7];
  const float* W_hh0  = (const float*)d_in[8];
  const float* b_ih0  = (const float*)d_in[9];
  const float* b_hh0  = (const float*)d_in[10];
  const float* W_ih1  = (const float*)d_in[11];
  const float* W_hh1  = (const float*)d_in[12];
  const float* b_ih1  = (const float*)d_in[13];
  const float* b_hh1  = (const float*)d_in[14];
  const float* W_out  = (const float*)d_in[15];
  const float* b_out  = (const float*)d_in[16];
  float* out = (float*)d_out;

  float* ws = (float*)d_ws;
  size_t off = 0;
  auto alloc = [&](size_t n){ float* p = ws + off; off += n; return p; };
  float* kp    = alloc((size_t)1024*1024);
  float* GX0x  = alloc((size_t)1024*3072);
  float* EW    = alloc((size_t)1024*3072);
  float* Whh0T = alloc((size_t)1024*3072);
  float* Whh1T = alloc((size_t)1024*3072);
  float* Wih1T = alloc((size_t)1024*3072);
  float* gh0   = alloc((size_t)16*3072);
  float* gh1   = alloc((size_t)16*3072);
  float* q     = alloc((size_t)16*1024);
  float* escore= alloc((size_t)16*64);
  float* h0a   = alloc((size_t)16*1024);
  float* h0b   = alloc((size_t)16*1024);
  float* h1a   = alloc((size_t)16*1024);
  float* h1b   = alloc((size_t)16*1024);
  float* Hseq  = alloc((size_t)1024*1024);
  float* Hb_f  = alloc((size_t)512*1024);
  float*  WkT     = Hseq;        // setup-only aliases
  float*  emb_tok = Hb_f;
  __bf16* Hb      = (__bf16*)Hb_f;
  (void)ws_size; (void)in_sizes; (void)n_in; (void)out_size;

  // ---- setup ----
  k_transpose<<<dim3(32,32),256,0,stream>>>(Wk,    WkT,   1024,1024);
  k_transpose<<<dim3(32,96),256,0,stream>>>(W_hh0, Whh0T, 3072,1024);
  k_transpose<<<dim3(32,96),256,0,stream>>>(W_hh1, Whh1T, 3072,1024);
  k_transpose<<<dim3(32,96),256,0,stream>>>(W_ih1, Wih1T, 3072,1024);
  k_gather<<<1024,256,0,stream>>>(tgt, emb, emb_tok);
  k_gemm_bt<<<dim3(16,16),256,0,stream>>>(enc,1024, WkT,1024, nullptr, kp, 1024,1024);
  k_gemm_bt<<<dim3(16,48),256,0,stream>>>(emb_tok,512, W_ih0,1536, b_ih0, GX0x, 3072,512);
  k_gemm_bt<<<dim3(16,48),256,0,stream>>>(enc,1024, W_ih0+512,1536, nullptr, EW, 3072,1024);
  k_boot<<<192,256,0,stream>>>(hidden, Whh0T, gh0);   // gh0 for t=0

  // ---- recurrence: 4 wide kernels per step ----
  const float* h0_init = hidden;
  const float* h1_init = hidden + 16*1024;
  for(int t=0;t<64;++t){
    const float* h0i = (t==0)? h0_init : ((t&1)? h0b : h0a);
    float*       h0o = (t&1)? h0a : h0b;
    const float* h1i = (t==0)? h1_init : ((t&1)? h1b : h1a);
    float*       h1o = (t&1)? h1a : h1b;
    k_step1<<<256,256,0,stream>>>(h1i, Whh1T, gh1, Wq, q);
    k_step2<<<256,256,0,stream>>>(q, kp, v_att, escore);
    k_step3<<<128,256,0,stream>>>(t, escore, EW, GX0x, gh0, b_hh0, h0i, h0o);
    k_step4<<<320,256,0,stream>>>(t, h0o, Wih1T, b_ih1, gh1, b_hh1, h1i, h1o, Hseq, Whh0T, gh0);
  }

  // ---- deferred logits ----
  k_cvt<<<(1024*1024)/256,256,0,stream>>>(Hseq, Hb);
  k_logits<<<1024,512,0,stream>>>(Hb, W_out, b_out, out);
}